// Round 1
// 694.129 us; speedup vs baseline: 1.3698x; 1.3698x over previous
//
#include <hip/hip_runtime.h>

#define BATCH 1024
#define SEQN  512
#define EMBD  50
#define HID   64
#define NC    50000
#define RPBK  16             // batch rows per LSTM block
#define HSTR  72             // h-tile row stride (fp16): 144B -> 2-way banks, 16B aligned
#define ESTR  72             // e-tile row stride (fp16), k padded 50->64 with zeros
#define NBLKX ((NC + 255) / 256)   // 196 col-blocks in FC

typedef _Float16 half8 __attribute__((ext_vector_type(8)));
typedef float    f32x4 __attribute__((ext_vector_type(4)));

// ---------------------------------------------------------------------------
// Recurrent LSTM: 64 blocks x 256 thr, 16 rows/block. K split:
//   critical path:  h(s) @ W_hh^T   (K=64, 2-deep MFMA chain)
//   off-path:       e(s+1) @ W_ih^T (K=64 padded, independent fill work)
// e-gather pipelined 3 deep: issue e(s+3) -> regs, write e(s+2) -> EB late,
// read e(s+1) for gx MFMA, consume gx(s) in epilogue. HS/EB double-buffered
// => ONE barrier per step. Gate cols permuted as before: col (64*nt+16*w+cc)
// so acc[nt][reg] = gate nt of unit u=16w+cc for row 4q+reg (register epilogue).
// ---------------------------------------------------------------------------
__global__ __launch_bounds__(256, 1)
void lstm_rec(const int* __restrict__ x, const float* __restrict__ emb,
              const float* __restrict__ W_ih, const float* __restrict__ W_hh,
              const float* __restrict__ b_ih, const float* __restrict__ b_hh,
              float* __restrict__ hF)
{
    __shared__ __align__(16) _Float16 HS[2][RPBK][HSTR];
    __shared__ __align__(16) _Float16 EB[2][RPBK][ESTR];
    __shared__ int xbuf[RPBK * SEQN];

    const int t    = threadIdx.x;
    const int w    = t >> 6;
    const int lane = t & 63;
    const int q    = lane >> 4;
    const int cc   = lane & 15;
    const int r0   = blockIdx.x * RPBK;
    const int u    = 16 * w + cc;

    // persistent B-fragments: W_hh^T (critical) and W_ih^T (k padded to 64)
    half8 Bh[2][4], Bi[2][4];
    float bias[4];
#pragma unroll
    for (int nt = 0; nt < 4; ++nt) {
        const int g = 64 * nt + u;
        bias[nt] = b_ih[g] + b_hh[g];
#pragma unroll
        for (int kt = 0; kt < 2; ++kt)
#pragma unroll
            for (int j = 0; j < 8; ++j) {
                const int k = 32 * kt + 8 * q + j;
                Bh[kt][nt][j] = (_Float16)W_hh[g * HID + k];
                Bi[kt][nt][j] = (k < EMBD) ? (_Float16)W_ih[g * EMBD + k] : (_Float16)0.0f;
            }
    }

    // stage token indices (coalesced); zero HS (h0=0) and EB (zero k-pad)
    for (int i = t; i < RPBK * SEQN; i += 256)
        xbuf[i] = x[(size_t)(r0 + (i >> 9)) * SEQN + (i & (SEQN - 1))];
    {
        _Float16* hz = &HS[0][0][0];
        for (int i = t; i < 2 * RPBK * HSTR; i += 256) hz[i] = (_Float16)0.0f;
        _Float16* ez = &EB[0][0][0];
        for (int i = t; i < 2 * RPBK * ESTR; i += 256) ez[i] = (_Float16)0.0f;
    }
    __syncthreads();

    // prologue: gather e(0),e(1),e(2); EB[0]<-e(0), EB[1]<-e(1); evB holds e(2)
    float evA[4] = {0, 0, 0, 0}, evB[4] = {0, 0, 0, 0};
    if (lane < EMBD) {
        float ev0[4], ev1[4];
#pragma unroll
        for (int ii = 0; ii < 4; ++ii) {
            const int m = w + 4 * ii;
            ev0[ii] = emb[(size_t)xbuf[m * SEQN + 0] * EMBD + lane];
            ev1[ii] = emb[(size_t)xbuf[m * SEQN + 1] * EMBD + lane];
            evB[ii] = emb[(size_t)xbuf[m * SEQN + 2] * EMBD + lane];
        }
#pragma unroll
        for (int ii = 0; ii < 4; ++ii) {
            const int m = w + 4 * ii;
            EB[0][m][lane] = (_Float16)ev0[ii];
            EB[1][m][lane] = (_Float16)ev1[ii];
        }
    }
    __syncthreads();

    // gx(0) = e(0) @ W_ih^T
    f32x4 gx[4], gxn[4];
    {
        const half8 Ae0 = *(const half8*)&EB[0][cc][8 * q];
        const half8 Ae1 = *(const half8*)&EB[0][cc][32 + 8 * q];
#pragma unroll
        for (int nt = 0; nt < 4; ++nt) {
            f32x4 z = (f32x4){0.f, 0.f, 0.f, 0.f};
            z = __builtin_amdgcn_mfma_f32_16x16x32_f16(Ae0, Bi[0][nt], z, 0, 0, 0);
            gx[nt] = __builtin_amdgcn_mfma_f32_16x16x32_f16(Ae1, Bi[1][nt], z, 0, 0, 0);
        }
    }
    __syncthreads();   // protect EB[0] before step-0 overwrites it with e(2)

    float cst[4] = {0.f, 0.f, 0.f, 0.f};
    float hreg[4];

    for (int s = 0; s < SEQN; ++s) {
        const int p = s & 1;

        // critical head: A-frags of h(s)
        const half8 Ah0 = *(const half8*)&HS[p][cc][8 * q];
        const half8 Ah1 = *(const half8*)&HS[p][cc][32 + 8 * q];

        // issue gathers for e(s+3) (independent; ~1.7 steps to complete)
        const int sg = (s + 3 < SEQN) ? s + 3 : SEQN - 1;
        if (lane < EMBD) {
#pragma unroll
            for (int ii = 0; ii < 4; ++ii) {
                const int m = w + 4 * ii;
                evA[ii] = emb[(size_t)xbuf[m * SEQN + sg] * EMBD + lane];
            }
        }

        // critical MFMAs: h(s) @ W_hh^T (2-deep chain, 4 independent nt)
        f32x4 acc[4];
#pragma unroll
        for (int nt = 0; nt < 4; ++nt) {
            f32x4 z = (f32x4){0.f, 0.f, 0.f, 0.f};
            z = __builtin_amdgcn_mfma_f32_16x16x32_f16(Ah0, Bh[0][nt], z, 0, 0, 0);
            acc[nt] = __builtin_amdgcn_mfma_f32_16x16x32_f16(Ah1, Bh[1][nt], z, 0, 0, 0);
        }

        // off-path: gx(s+1) = e(s+1) @ W_ih^T from EB[(s+1)&1]
        {
            const int pe = (s + 1) & 1;
            const half8 Ae0 = *(const half8*)&EB[pe][cc][8 * q];
            const half8 Ae1 = *(const half8*)&EB[pe][cc][32 + 8 * q];
#pragma unroll
            for (int nt = 0; nt < 4; ++nt) {
                f32x4 z = (f32x4){0.f, 0.f, 0.f, 0.f};
                z = __builtin_amdgcn_mfma_f32_16x16x32_f16(Ae0, Bi[0][nt], z, 0, 0, 0);
                gxn[nt] = __builtin_amdgcn_mfma_f32_16x16x32_f16(Ae1, Bi[1][nt], z, 0, 0, 0);
            }
        }

        // register-only gate epilogue (fast rcp instead of IEEE divides)
#pragma unroll
        for (int reg = 0; reg < 4; ++reg) {
            const float gi = acc[0][reg] + gx[0][reg] + bias[0];
            const float gf = acc[1][reg] + gx[1][reg] + bias[1];
            const float gg = acc[2][reg] + gx[2][reg] + bias[2];
            const float go = acc[3][reg] + gx[3][reg] + bias[3];
            const float i_ = __builtin_amdgcn_rcpf(1.0f + __expf(-gi));
            const float f_ = __builtin_amdgcn_rcpf(1.0f + __expf(-gf));
            const float g_ = 1.0f - 2.0f * __builtin_amdgcn_rcpf(__expf(2.0f * gg) + 1.0f);
            const float o_ = __builtin_amdgcn_rcpf(1.0f + __expf(-go));
            cst[reg] = fmaf(f_, cst[reg], i_ * g_);
            hreg[reg] = o_ * (1.0f - 2.0f * __builtin_amdgcn_rcpf(__expf(2.0f * cst[reg]) + 1.0f));
        }

        // writes: h(s+1) -> HS[p^1]; e(s+2) -> EB[p] (both unread this step)
#pragma unroll
        for (int reg = 0; reg < 4; ++reg)
            HS[p ^ 1][4 * q + reg][u] = (_Float16)hreg[reg];
        if (lane < EMBD) {
#pragma unroll
            for (int ii = 0; ii < 4; ++ii) {
                const int m = w + 4 * ii;
                EB[p][m][lane] = (_Float16)evB[ii];
            }
        }
        if (s == SEQN - 1) {
#pragma unroll
            for (int reg = 0; reg < 4; ++reg)
                hF[(size_t)(r0 + 4 * q + reg) * HID + u] = hreg[reg];
        }
        __syncthreads();   // the ONE barrier per step

        // rotate pipeline registers
#pragma unroll
        for (int nt = 0; nt < 4; ++nt) gx[nt] = gxn[nt];
#pragma unroll
        for (int ii = 0; ii < 4; ++ii) evB[ii] = evA[ii];
    }
}

// ---------------------------------------------------------------------------
// FC + softmax, two-pass MFMA recompute (no max: |logit| < ~4).
//   pass A (WRITE=false): block-local row-sums of exp(logits) -> Sp[bx][row]
//   reduce_s            : S[row] = 1 / sum_bx Sp[bx][row]
//   pass B (WRITE=true) : out = exp(logit) * S[row]
// No global atomics (was 800K fp32 atomicAdds onto 4KB of S).
// ---------------------------------------------------------------------------
__global__ void reduce_s(const float* __restrict__ Sp, float* __restrict__ S) {
    const int r = blockIdx.x * 256 + threadIdx.x;
    if (r < BATCH) {
        float v = 0.0f;
        for (int j = 0; j < NBLKX; ++j) v += Sp[(size_t)j * BATCH + r];
        S[r] = 1.0f / v;
    }
}

template <bool WRITE>
__global__ __launch_bounds__(256, 2)
void fc_pass(const float* __restrict__ hF, const float* __restrict__ W_fc,
             const float* __restrict__ b_fc, float* __restrict__ Sv,
             float* __restrict__ out)
{
    __shared__ float sinv[64];
    __shared__ float sred[4][64];
    const int t    = threadIdx.x;
    const int w    = t >> 6;
    const int lane = t & 63;
    const int q    = lane >> 4;
    const int cc   = lane & 15;
    const int row0 = blockIdx.y * 64;
    const int n0   = blockIdx.x * 256;

    if (WRITE) {
        if (t < 64) sinv[t] = Sv[row0 + t];   // Sv already holds 1/sum
        __syncthreads();
    }

    // A-frags: h rows (fp32 -> fp16), [mt][kt]
    half8 Af[4][2];
#pragma unroll
    for (int mt = 0; mt < 4; ++mt)
#pragma unroll
        for (int kt = 0; kt < 2; ++kt) {
            const float* p = hF + (size_t)(row0 + 16 * mt + cc) * HID + 32 * kt + 8 * q;
#pragma unroll
            for (int j = 0; j < 8; ++j) Af[mt][kt][j] = (_Float16)p[j];
        }

    // B-frags: W_fc rows (cols of logits), clamped at NC
    half8 Bf[4][2];
    float bias[4];
#pragma unroll
    for (int nt = 0; nt < 4; ++nt) {
        int n = n0 + 64 * w + 16 * nt + cc;
        const int nl = (n < NC) ? n : NC - 1;
        bias[nt] = b_fc[nl];
#pragma unroll
        for (int kt = 0; kt < 2; ++kt) {
            const float* p = W_fc + (size_t)nl * HID + 32 * kt + 8 * q;
#pragma unroll
            for (int j = 0; j < 8; ++j) Bf[nt][kt][j] = (_Float16)p[j];
        }
    }

    f32x4 acc[4][4];   // [mt][nt]
#pragma unroll
    for (int mt = 0; mt < 4; ++mt)
#pragma unroll
        for (int nt = 0; nt < 4; ++nt) acc[mt][nt] = (f32x4){0.f, 0.f, 0.f, 0.f};
#pragma unroll
    for (int mt = 0; mt < 4; ++mt)
#pragma unroll
        for (int nt = 0; nt < 4; ++nt)
#pragma unroll
            for (int kt = 0; kt < 2; ++kt)
                acc[mt][nt] = __builtin_amdgcn_mfma_f32_16x16x32_f16(Af[mt][kt], Bf[nt][kt], acc[mt][nt], 0, 0, 0);

    if (!WRITE) {
        float rs[4][4];   // [mt][reg] partial row-sums over this wave's 64 cols
#pragma unroll
        for (int mt = 0; mt < 4; ++mt)
#pragma unroll
            for (int reg = 0; reg < 4; ++reg) rs[mt][reg] = 0.0f;
#pragma unroll
        for (int mt = 0; mt < 4; ++mt)
#pragma unroll
            for (int nt = 0; nt < 4; ++nt) {
                const int n = n0 + 64 * w + 16 * nt + cc;
#pragma unroll
                for (int reg = 0; reg < 4; ++reg) {
                    const float l = acc[mt][nt][reg] + bias[nt];
                    rs[mt][reg] += (n < NC) ? __expf(l) : 0.0f;
                }
            }
#pragma unroll
        for (int mt = 0; mt < 4; ++mt)
#pragma unroll
            for (int reg = 0; reg < 4; ++reg) {
                float v = rs[mt][reg];
                v += __shfl_xor(v, 1);
                v += __shfl_xor(v, 2);
                v += __shfl_xor(v, 4);
                v += __shfl_xor(v, 8);
                rs[mt][reg] = v;
            }
        if (cc == 0) {
#pragma unroll
            for (int mt = 0; mt < 4; ++mt)
#pragma unroll
                for (int reg = 0; reg < 4; ++reg)
                    sred[w][16 * mt + 4 * q + reg] = rs[mt][reg];
        }
        __syncthreads();
        if (t < 64)
            Sv[(size_t)blockIdx.x * BATCH + row0 + t] =
                sred[0][t] + sred[1][t] + sred[2][t] + sred[3][t];
    } else {
#pragma unroll
        for (int mt = 0; mt < 4; ++mt) {
            float si[4];
#pragma unroll
            for (int reg = 0; reg < 4; ++reg) si[reg] = sinv[16 * mt + 4 * q + reg];
#pragma unroll
            for (int nt = 0; nt < 4; ++nt) {
                const int n = n0 + 64 * w + 16 * nt + cc;
                if (n < NC) {
#pragma unroll
                    for (int reg = 0; reg < 4; ++reg) {
                        const float l = acc[mt][nt][reg] + bias[nt];
                        out[(size_t)(row0 + 16 * mt + 4 * q + reg) * NC + n] = __expf(l) * si[reg];
                    }
                }
            }
        }
    }
}

extern "C" void kernel_launch(void* const* d_in, const int* in_sizes, int n_in,
                              void* d_out, int out_size, void* d_ws, size_t ws_size,
                              hipStream_t stream) {
    (void)in_sizes; (void)n_in; (void)out_size; (void)ws_size;
    const int*   x    = (const int*)  d_in[0];
    const float* emb  = (const float*)d_in[1];
    const float* W_ih = (const float*)d_in[2];
    const float* W_hh = (const float*)d_in[3];
    const float* b_ih = (const float*)d_in[4];
    const float* b_hh = (const float*)d_in[5];
    const float* W_fc = (const float*)d_in[6];
    const float* b_fc = (const float*)d_in[7];
    float* out = (float*)d_out;

    float* hF = (float*)d_ws;          // 1024*64 fp32 = 256 KB
    float* S  = hF + BATCH * HID;      // 1024 fp32
    float* Sp = S + BATCH;             // 196*1024 fp32 partial sums (~784 KB)

    hipLaunchKernelGGL(lstm_rec, dim3(BATCH / RPBK), dim3(256), 0, stream,
                       x, emb, W_ih, W_hh, b_ih, b_hh, hF);
    dim3 g2(NBLKX, BATCH / 64);   // (196, 16)
    hipLaunchKernelGGL(fc_pass<false>, g2, dim3(256), 0, stream, hF, W_fc, b_fc, Sp, out);
    hipLaunchKernelGGL(reduce_s, dim3(4), dim3(256), 0, stream, Sp, S);
    hipLaunchKernelGGL(fc_pass<true>,  g2, dim3(256), 0, stream, hF, W_fc, b_fc, S, out);
}

// Round 2
// 648.290 us; speedup vs baseline: 1.4667x; 1.0707x over previous
//
#include <hip/hip_runtime.h>

#define BATCH 1024
#define SEQN  512
#define EMBD  50
#define HID   64
#define NC    50000
#define RPBK  16             // batch rows per LSTM block
#define HSTR  72             // h-tile row stride (fp16)
#define ESTR  72             // e-tile row stride (fp16), k padded 50->64 with zeros
#define NBLKX ((NC + 255) / 256)   // 196 col-blocks in FC

typedef _Float16 half8 __attribute__((ext_vector_type(8)));
typedef float    f32x4 __attribute__((ext_vector_type(4)));

// barrier that does NOT drain vmcnt: LDS ordering via lgkmcnt(0) only.
// The in-flight global gathers (vmcnt) deliberately stay outstanding.
__device__ __forceinline__ void barrier_lds_only() {
    asm volatile("s_waitcnt lgkmcnt(0)\n\ts_barrier" ::: "memory");
}

// ---------------------------------------------------------------------------
// Recurrent LSTM: 64 blocks x 256 thr, 16 rows/block.
//   critical path:  h(s) @ W_hh^T   (K=64, 2-deep MFMA chain)
//   off-path:       e(s+1) @ W_ih^T (independent fill work)
// 2x manual unroll, gather pipelined 4 steps deep with explicit ping-pong
// regs (eA/eB): gather issued at step s is consumed (LDS write) at step s+2,
// and the in-loop barrier does not drain vmcnt -> gather latency fully hidden.
// ---------------------------------------------------------------------------
__global__ __launch_bounds__(256, 1)
void lstm_rec(const int* __restrict__ x, const float* __restrict__ emb,
              const float* __restrict__ W_ih, const float* __restrict__ W_hh,
              const float* __restrict__ b_ih, const float* __restrict__ b_hh,
              _Float16* __restrict__ hFh)
{
    __shared__ __align__(16) _Float16 HS[2][RPBK][HSTR];
    __shared__ __align__(16) _Float16 EB[2][RPBK][ESTR];
    __shared__ int xbuf[RPBK * SEQN];

    const int t    = threadIdx.x;
    const int w    = t >> 6;
    const int lane = t & 63;
    const int q    = lane >> 4;
    const int cc   = lane & 15;
    const int r0   = blockIdx.x * RPBK;
    const int u    = 16 * w + cc;

    // persistent B-fragments: W_hh^T (critical) and W_ih^T (k padded to 64)
    half8 Bh[2][4], Bi[2][4];
    float bias[4];
#pragma unroll
    for (int nt = 0; nt < 4; ++nt) {
        const int g = 64 * nt + u;
        bias[nt] = b_ih[g] + b_hh[g];
#pragma unroll
        for (int kt = 0; kt < 2; ++kt)
#pragma unroll
            for (int j = 0; j < 8; ++j) {
                const int k = 32 * kt + 8 * q + j;
                Bh[kt][nt][j] = (_Float16)W_hh[g * HID + k];
                Bi[kt][nt][j] = (k < EMBD) ? (_Float16)W_ih[g * EMBD + k] : (_Float16)0.0f;
            }
    }

    // stage token indices (coalesced); zero HS (h0=0) and EB (zero k-pad)
    for (int i = t; i < RPBK * SEQN; i += 256)
        xbuf[i] = x[(size_t)(r0 + (i >> 9)) * SEQN + (i & (SEQN - 1))];
    {
        _Float16* hz = &HS[0][0][0];
        for (int i = t; i < 2 * RPBK * HSTR; i += 256) hz[i] = (_Float16)0.0f;
        _Float16* ez = &EB[0][0][0];
        for (int i = t; i < 2 * RPBK * ESTR; i += 256) ez[i] = (_Float16)0.0f;
    }
    __syncthreads();

    // prologue: gather e(0..3); EB[0]<-e(0), EB[1]<-e(1); eA=e(2), eB=e(3)
    float eA[4] = {0, 0, 0, 0}, eB[4] = {0, 0, 0, 0};
    if (lane < EMBD) {
        float e0v[4], e1v[4];
#pragma unroll
        for (int ii = 0; ii < 4; ++ii) {
            const int m = w + 4 * ii;
            e0v[ii] = emb[(size_t)xbuf[m * SEQN + 0] * EMBD + lane];
            e1v[ii] = emb[(size_t)xbuf[m * SEQN + 1] * EMBD + lane];
            eA[ii]  = emb[(size_t)xbuf[m * SEQN + 2] * EMBD + lane];
            eB[ii]  = emb[(size_t)xbuf[m * SEQN + 3] * EMBD + lane];
        }
#pragma unroll
        for (int ii = 0; ii < 4; ++ii) {
            const int m = w + 4 * ii;
            EB[0][m][lane] = (_Float16)e0v[ii];
            EB[1][m][lane] = (_Float16)e1v[ii];
        }
    }
    __syncthreads();

    // gx(0) = e(0) @ W_ih^T
    f32x4 gxA[4], gxB[4];
    {
        const half8 Ae0 = *(const half8*)&EB[0][cc][8 * q];
        const half8 Ae1 = *(const half8*)&EB[0][cc][32 + 8 * q];
#pragma unroll
        for (int nt = 0; nt < 4; ++nt) {
            f32x4 z = (f32x4){0.f, 0.f, 0.f, 0.f};
            z = __builtin_amdgcn_mfma_f32_16x16x32_f16(Ae0, Bi[0][nt], z, 0, 0, 0);
            gxA[nt] = __builtin_amdgcn_mfma_f32_16x16x32_f16(Ae1, Bi[1][nt], z, 0, 0, 0);
        }
    }
    __syncthreads();   // EB[0] about to be overwritten at step 0

    float cst[4] = {0.f, 0.f, 0.f, 0.f};
    float hreg[4];

    // one step; EREG holds e(s+2) on entry, refilled with gather of e(s+4).
    // GXIN = gx(s) (consumed), GXOUT = gx(s+1) (produced).
#define LSTM_STEP(S, P, EREG, GXIN, GXOUT) do {                                   \
        /* write EB[P] <- e(s+2); consumes gather issued 2 steps ago */           \
        if (lane < EMBD) {                                                        \
            _Pragma("unroll")                                                     \
            for (int ii = 0; ii < 4; ++ii)                                        \
                EB[P][w + 4 * ii][lane] = (_Float16)EREG[ii];                     \
        }                                                                         \
        /* critical head: A-frags of h(s) */                                      \
        const half8 Ah0 = *(const half8*)&HS[P][cc][8 * q];                       \
        const half8 Ah1 = *(const half8*)&HS[P][cc][32 + 8 * q];                  \
        /* issue gather for e(s+4); completes within ~2 steps */                  \
        {                                                                         \
            const int sg = ((S) + 4 < SEQN) ? (S) + 4 : SEQN - 1;                 \
            if (lane < EMBD) {                                                    \
                _Pragma("unroll")                                                 \
                for (int ii = 0; ii < 4; ++ii)                                    \
                    EREG[ii] = emb[(size_t)xbuf[(w + 4 * ii) * SEQN + sg] * EMBD + lane]; \
            }                                                                     \
        }                                                                         \
        /* critical MFMAs: h(s) @ W_hh^T */                                       \
        f32x4 acc[4];                                                             \
        _Pragma("unroll")                                                         \
        for (int nt = 0; nt < 4; ++nt) {                                          \
            f32x4 z = (f32x4){0.f, 0.f, 0.f, 0.f};                                \
            z = __builtin_amdgcn_mfma_f32_16x16x32_f16(Ah0, Bh[0][nt], z, 0, 0, 0); \
            acc[nt] = __builtin_amdgcn_mfma_f32_16x16x32_f16(Ah1, Bh[1][nt], z, 0, 0, 0); \
        }                                                                         \
        /* off-path: gx(s+1) = e(s+1) @ W_ih^T from EB[P^1] */                    \
        {                                                                         \
            const half8 Ae0 = *(const half8*)&EB[(P) ^ 1][cc][8 * q];             \
            const half8 Ae1 = *(const half8*)&EB[(P) ^ 1][cc][32 + 8 * q];        \
            _Pragma("unroll")                                                     \
            for (int nt = 0; nt < 4; ++nt) {                                      \
                f32x4 z = (f32x4){0.f, 0.f, 0.f, 0.f};                            \
                z = __builtin_amdgcn_mfma_f32_16x16x32_f16(Ae0, Bi[0][nt], z, 0, 0, 0); \
                GXOUT[nt] = __builtin_amdgcn_mfma_f32_16x16x32_f16(Ae1, Bi[1][nt], z, 0, 0, 0); \
            }                                                                     \
        }                                                                         \
        /* register-only gate epilogue */                                         \
        _Pragma("unroll")                                                         \
        for (int reg = 0; reg < 4; ++reg) {                                       \
            const float gi = acc[0][reg] + GXIN[0][reg] + bias[0];                \
            const float gf = acc[1][reg] + GXIN[1][reg] + bias[1];                \
            const float gg = acc[2][reg] + GXIN[2][reg] + bias[2];                \
            const float go = acc[3][reg] + GXIN[3][reg] + bias[3];                \
            const float i_ = __builtin_amdgcn_rcpf(1.0f + __expf(-gi));           \
            const float f_ = __builtin_amdgcn_rcpf(1.0f + __expf(-gf));           \
            const float g_ = 1.0f - 2.0f * __builtin_amdgcn_rcpf(__expf(2.0f * gg) + 1.0f); \
            const float o_ = __builtin_amdgcn_rcpf(1.0f + __expf(-go));           \
            cst[reg] = fmaf(f_, cst[reg], i_ * g_);                               \
            hreg[reg] = o_ * (1.0f - 2.0f * __builtin_amdgcn_rcpf(__expf(2.0f * cst[reg]) + 1.0f)); \
        }                                                                         \
        /* write h(s+1) */                                                        \
        _Pragma("unroll")                                                         \
        for (int reg = 0; reg < 4; ++reg)                                         \
            HS[(P) ^ 1][4 * q + reg][u] = (_Float16)hreg[reg];                    \
        if ((S) == SEQN - 1) {                                                    \
            _Pragma("unroll")                                                     \
            for (int reg = 0; reg < 4; ++reg)                                     \
                hFh[(size_t)(r0 + 4 * q + reg) * HID + u] = (_Float16)hreg[reg];  \
        }                                                                         \
        barrier_lds_only();                                                       \
    } while (0)

    for (int s2 = 0; s2 < SEQN; s2 += 2) {
        LSTM_STEP(s2,     0, eA, gxA, gxB);
        LSTM_STEP(s2 + 1, 1, eB, gxB, gxA);
    }
#undef LSTM_STEP
}

// ---------------------------------------------------------------------------
// FC + softmax, two-pass MFMA recompute (no max: |logit| < ~4).
// 196 blocks; each block owns 256 logit-cols with PERSISTENT W_fc B-frags and
// loops over all 16 row-groups -> W_fc read ONCE total (12.8 MB, was 205 MB).
//   pass A (WRITE=false): block-local row-sums of exp(logits) -> Sp[bx][row]
//   reduce_s            : S[row] = 1 / sum_bx Sp[bx][row]
//   pass B (WRITE=true) : out = exp(logit) * S[row]
// ---------------------------------------------------------------------------
__global__ void reduce_s(const float* __restrict__ Sp, float* __restrict__ S) {
    const int r = blockIdx.x * 256 + threadIdx.x;
    if (r < BATCH) {
        float v = 0.0f;
        for (int j = 0; j < NBLKX; ++j) v += Sp[(size_t)j * BATCH + r];
        S[r] = 1.0f / v;
    }
}

template <bool WRITE>
__global__ __launch_bounds__(256, 2)
void fc_pass(const _Float16* __restrict__ hFh, const float* __restrict__ W_fc,
             const float* __restrict__ b_fc, float* __restrict__ Sv,
             float* __restrict__ out)
{
    __shared__ float sinv[BATCH];    // pass B: 1/S for all rows (4 KB)
    __shared__ float sred[4][64];
    const int t    = threadIdx.x;
    const int w    = t >> 6;
    const int lane = t & 63;
    const int q    = lane >> 4;
    const int cc   = lane & 15;
    const int n0   = blockIdx.x * 256;

    if (WRITE) {
        for (int i = t; i < BATCH; i += 256) sinv[i] = Sv[i];
        __syncthreads();
    }

    // persistent B-frags: W_fc rows (cols of logits), clamped at NC
    half8 Bf[4][2];
    float bias[4];
#pragma unroll
    for (int nt = 0; nt < 4; ++nt) {
        int n = n0 + 64 * w + 16 * nt + cc;
        const int nl = (n < NC) ? n : NC - 1;
        bias[nt] = b_fc[nl];
#pragma unroll
        for (int kt = 0; kt < 2; ++kt) {
            const float* p = W_fc + (size_t)nl * HID + 32 * kt + 8 * q;
#pragma unroll
            for (int j = 0; j < 8; ++j) Bf[nt][kt][j] = (_Float16)p[j];
        }
    }

    for (int rg = 0; rg < BATCH / 64; ++rg) {
        const int row0 = rg * 64;

        // A-frags: h rows, fp16 direct
        half8 Af[4][2];
#pragma unroll
        for (int mt = 0; mt < 4; ++mt)
#pragma unroll
            for (int kt = 0; kt < 2; ++kt)
                Af[mt][kt] = *(const half8*)&hFh[(size_t)(row0 + 16 * mt + cc) * HID + 32 * kt + 8 * q];

        f32x4 acc[4][4];   // [mt][nt]
#pragma unroll
        for (int mt = 0; mt < 4; ++mt)
#pragma unroll
            for (int nt = 0; nt < 4; ++nt) acc[mt][nt] = (f32x4){0.f, 0.f, 0.f, 0.f};
#pragma unroll
        for (int mt = 0; mt < 4; ++mt)
#pragma unroll
            for (int nt = 0; nt < 4; ++nt)
#pragma unroll
                for (int kt = 0; kt < 2; ++kt)
                    acc[mt][nt] = __builtin_amdgcn_mfma_f32_16x16x32_f16(Af[mt][kt], Bf[nt][kt], acc[mt][nt], 0, 0, 0);

        if (!WRITE) {
            float rs[4][4];   // [mt][reg] partial row-sums over this wave's 64 cols
#pragma unroll
            for (int mt = 0; mt < 4; ++mt)
#pragma unroll
                for (int reg = 0; reg < 4; ++reg) rs[mt][reg] = 0.0f;
#pragma unroll
            for (int mt = 0; mt < 4; ++mt)
#pragma unroll
                for (int nt = 0; nt < 4; ++nt) {
                    const int n = n0 + 64 * w + 16 * nt + cc;
#pragma unroll
                    for (int reg = 0; reg < 4; ++reg) {
                        const float l = acc[mt][nt][reg] + bias[nt];
                        rs[mt][reg] += (n < NC) ? __expf(l) : 0.0f;
                    }
                }
#pragma unroll
            for (int mt = 0; mt < 4; ++mt)
#pragma unroll
                for (int reg = 0; reg < 4; ++reg) {
                    float v = rs[mt][reg];
                    v += __shfl_xor(v, 1);
                    v += __shfl_xor(v, 2);
                    v += __shfl_xor(v, 4);
                    v += __shfl_xor(v, 8);
                    rs[mt][reg] = v;
                }
            if (cc == 0) {
#pragma unroll
                for (int mt = 0; mt < 4; ++mt)
#pragma unroll
                    for (int reg = 0; reg < 4; ++reg)
                        sred[w][16 * mt + 4 * q + reg] = rs[mt][reg];
            }
            __syncthreads();
            if (t < 64)
                Sv[(size_t)blockIdx.x * BATCH + row0 + t] =
                    sred[0][t] + sred[1][t] + sred[2][t] + sred[3][t];
            __syncthreads();   // sred reused next rg
        } else {
#pragma unroll
            for (int mt = 0; mt < 4; ++mt) {
                float si[4];
#pragma unroll
                for (int reg = 0; reg < 4; ++reg) si[reg] = sinv[row0 + 16 * mt + 4 * q + reg];
#pragma unroll
                for (int nt = 0; nt < 4; ++nt) {
                    const int n = n0 + 64 * w + 16 * nt + cc;
                    if (n < NC) {
#pragma unroll
                        for (int reg = 0; reg < 4; ++reg) {
                            const float l = acc[mt][nt][reg] + bias[nt];
                            out[(size_t)(row0 + 16 * mt + 4 * q + reg) * NC + n] = __expf(l) * si[reg];
                        }
                    }
                }
            }
        }
    }
}

extern "C" void kernel_launch(void* const* d_in, const int* in_sizes, int n_in,
                              void* d_out, int out_size, void* d_ws, size_t ws_size,
                              hipStream_t stream) {
    (void)in_sizes; (void)n_in; (void)out_size; (void)ws_size;
    const int*   x    = (const int*)  d_in[0];
    const float* emb  = (const float*)d_in[1];
    const float* W_ih = (const float*)d_in[2];
    const float* W_hh = (const float*)d_in[3];
    const float* b_ih = (const float*)d_in[4];
    const float* b_hh = (const float*)d_in[5];
    const float* W_fc = (const float*)d_in[6];
    const float* b_fc = (const float*)d_in[7];
    float* out = (float*)d_out;

    _Float16* hFh = (_Float16*)d_ws;                                  // 128 KB
    float* S  = (float*)((char*)d_ws + (size_t)BATCH * HID * 2);      // 4 KB
    float* Sp = S + BATCH;                                            // 196*1024 f32

    hipLaunchKernelGGL(lstm_rec, dim3(BATCH / RPBK), dim3(256), 0, stream,
                       x, emb, W_ih, W_hh, b_ih, b_hh, hFh);
    hipLaunchKernelGGL(fc_pass<false>, dim3(NBLKX), dim3(256), 0, stream,
                       hFh, W_fc, b_fc, Sp, out);
    hipLaunchKernelGGL(reduce_s, dim3(4), dim3(256), 0, stream, Sp, S);
    hipLaunchKernelGGL(fc_pass<true>,  dim3(NBLKX), dim3(256), 0, stream,
                       hFh, W_fc, b_fc, S, out);
}

// Round 3
// 632.802 us; speedup vs baseline: 1.5026x; 1.0245x over previous
//
#include <hip/hip_runtime.h>

#define BATCH 1024
#define SEQN  512
#define EMBD  50
#define HID   64
#define NC    50000
#define RPBK  2              // batch rows per LSTM block -> 512 blocks, 2/CU
#define HSTR  72             // h-tile row stride (fp16)
#define ESTR  72             // e-tile row stride (fp16)
#define NBLKX ((NC + 255) / 256)   // 196 col-blocks in FC

typedef _Float16 half8 __attribute__((ext_vector_type(8)));
typedef float    f32x4 __attribute__((ext_vector_type(4)));

// barrier that does NOT drain vmcnt: LDS ordering via lgkmcnt(0) only.
__device__ __forceinline__ void barrier_lds_only() {
    asm volatile("s_waitcnt lgkmcnt(0)\n\ts_barrier" ::: "memory");
}

// ---------------------------------------------------------------------------
// Recurrent LSTM: 512 blocks x 256 thr, 2 rows/block (2 blocks/CU for TLP).
//   critical path:  h(s) @ W_hh^T   (K=64, 2-deep MFMA chain)
//   off-path:       e(s+1) @ W_ih^T (independent fill work)
// Gate-sets redistributed one-per-lane via 8 shuffles: trans issue per wave
// drops 4x vs packing 4 sets/lane. Gather pipelined 4 deep (2x unroll,
// ping-pong regs); in-loop barrier keeps gathers vmcnt-outstanding.
// ---------------------------------------------------------------------------
__global__ __launch_bounds__(256, 2)
void lstm_rec(const int* __restrict__ x, const float* __restrict__ emb,
              const float* __restrict__ W_ih, const float* __restrict__ W_hh,
              const float* __restrict__ b_ih, const float* __restrict__ b_hh,
              _Float16* __restrict__ hFh)
{
    __shared__ __align__(16) _Float16 HS[2][16][HSTR];   // rows 2..15 stay 0
    __shared__ __align__(16) _Float16 EB[2][16][ESTR];   // rows 2..15 stay 0
    __shared__ int xbuf[RPBK * SEQN];

    const int t    = threadIdx.x;
    const int w    = t >> 6;
    const int lane = t & 63;
    const int q    = lane >> 4;
    const int cc   = lane & 15;
    const int r0   = blockIdx.x * RPBK;
    const int u    = 16 * w + cc;

    // persistent B-fragments: W_hh^T (critical) and W_ih^T (k padded to 64)
    half8 Bh[2][4], Bi[2][4];
    float bias[4];
#pragma unroll
    for (int nt = 0; nt < 4; ++nt) {
        const int g = 64 * nt + u;
        bias[nt] = b_ih[g] + b_hh[g];
#pragma unroll
        for (int kt = 0; kt < 2; ++kt)
#pragma unroll
            for (int j = 0; j < 8; ++j) {
                const int k = 32 * kt + 8 * q + j;
                Bh[kt][nt][j] = (_Float16)W_hh[g * HID + k];
                Bi[kt][nt][j] = (k < EMBD) ? (_Float16)W_ih[g * EMBD + k] : (_Float16)0.0f;
            }
    }

    // stage token indices; zero HS (h0=0, pad rows) and EB (pad rows/k)
    for (int i = t; i < RPBK * SEQN; i += 256)
        xbuf[i] = x[(size_t)(r0 + (i >> 9)) * SEQN + (i & (SEQN - 1))];
    {
        _Float16* hz = &HS[0][0][0];
        for (int i = t; i < 2 * 16 * HSTR; i += 256) hz[i] = (_Float16)0.0f;
        _Float16* ez = &EB[0][0][0];
        for (int i = t; i < 2 * 16 * ESTR; i += 256) ez[i] = (_Float16)0.0f;
    }
    __syncthreads();

    // prologue: wave w<2 gathers e(0..3) for row w; EB[0]<-e(0), EB[1]<-e(1)
    float eA = 0.0f, eB = 0.0f;
    if (w < 2 && lane < EMBD) {
        const float e0 = emb[(size_t)xbuf[w * SEQN + 0] * EMBD + lane];
        const float e1 = emb[(size_t)xbuf[w * SEQN + 1] * EMBD + lane];
        eA = emb[(size_t)xbuf[w * SEQN + 2] * EMBD + lane];
        eB = emb[(size_t)xbuf[w * SEQN + 3] * EMBD + lane];
        EB[0][w][lane] = (_Float16)e0;
        EB[1][w][lane] = (_Float16)e1;
    }
    __syncthreads();

    // gx(0) = e(0) @ W_ih^T
    f32x4 gxA[4], gxB[4];
    {
        const half8 Ae0 = *(const half8*)&EB[0][cc][8 * q];
        const half8 Ae1 = *(const half8*)&EB[0][cc][32 + 8 * q];
#pragma unroll
        for (int nt = 0; nt < 4; ++nt) {
            f32x4 z = (f32x4){0.f, 0.f, 0.f, 0.f};
            z = __builtin_amdgcn_mfma_f32_16x16x32_f16(Ae0, Bi[0][nt], z, 0, 0, 0);
            gxA[nt] = __builtin_amdgcn_mfma_f32_16x16x32_f16(Ae1, Bi[1][nt], z, 0, 0, 0);
        }
    }
    __syncthreads();   // EB[0] about to be overwritten at step 0

    float cst = 0.0f;  // c for (row q, unit u) -- valid on lanes q<2

    // one step; EREG holds e(s+2) on entry, refilled with gather of e(s+4).
#define LSTM_STEP(S, P, EREG, GXIN, GXOUT) do {                                   \
        /* write EB[P] <- e(s+2); consumes gather issued 2 steps ago */           \
        if (w < 2 && lane < EMBD)                                                 \
            EB[P][w][lane] = (_Float16)EREG;                                      \
        /* critical head: A-frags of h(s) */                                      \
        const half8 Ah0 = *(const half8*)&HS[P][cc][8 * q];                       \
        const half8 Ah1 = *(const half8*)&HS[P][cc][32 + 8 * q];                  \
        /* issue gather for e(s+4) */                                             \
        {                                                                         \
            const int sg = ((S) + 4 < SEQN) ? (S) + 4 : SEQN - 1;                 \
            if (w < 2 && lane < EMBD)                                             \
                EREG = emb[(size_t)xbuf[w * SEQN + sg] * EMBD + lane];            \
        }                                                                         \
        /* critical MFMAs: h(s) @ W_hh^T */                                       \
        f32x4 acc[4];                                                             \
        _Pragma("unroll")                                                         \
        for (int nt = 0; nt < 4; ++nt) {                                          \
            f32x4 z = (f32x4){0.f, 0.f, 0.f, 0.f};                                \
            z = __builtin_amdgcn_mfma_f32_16x16x32_f16(Ah0, Bh[0][nt], z, 0, 0, 0); \
            acc[nt] = __builtin_amdgcn_mfma_f32_16x16x32_f16(Ah1, Bh[1][nt], z, 0, 0, 0); \
        }                                                                         \
        /* off-path: gx(s+1) = e(s+1) @ W_ih^T from EB[P^1] */                    \
        {                                                                         \
            const half8 Ae0 = *(const half8*)&EB[(P) ^ 1][cc][8 * q];             \
            const half8 Ae1 = *(const half8*)&EB[(P) ^ 1][cc][32 + 8 * q];        \
            _Pragma("unroll")                                                     \
            for (int nt = 0; nt < 4; ++nt) {                                      \
                f32x4 z = (f32x4){0.f, 0.f, 0.f, 0.f};                            \
                z = __builtin_amdgcn_mfma_f32_16x16x32_f16(Ae0, Bi[0][nt], z, 0, 0, 0); \
                GXOUT[nt] = __builtin_amdgcn_mfma_f32_16x16x32_f16(Ae1, Bi[1][nt], z, 0, 0, 0); \
            }                                                                     \
        }                                                                         \
        /* redistribute: lane (q,cc) takes (row q, unit u) preacts, q<2 valid */  \
        float pre[4];                                                             \
        _Pragma("unroll")                                                         \
        for (int nt = 0; nt < 4; ++nt) {                                          \
            const float s0 = acc[nt][0] + GXIN[nt][0];                            \
            const float s1 = acc[nt][1] + GXIN[nt][1];                            \
            const float v0 = __shfl(s0, cc);                                      \
            const float v1 = __shfl(s1, cc);                                      \
            pre[nt] = ((q == 0) ? v0 : v1) + bias[nt];                            \
        }                                                                         \
        /* one gate-set epilogue per lane */                                      \
        const float i_ = __builtin_amdgcn_rcpf(1.0f + __expf(-pre[0]));           \
        const float f_ = __builtin_amdgcn_rcpf(1.0f + __expf(-pre[1]));           \
        const float g_ = 1.0f - 2.0f * __builtin_amdgcn_rcpf(__expf(2.0f * pre[2]) + 1.0f); \
        const float o_ = __builtin_amdgcn_rcpf(1.0f + __expf(-pre[3]));           \
        cst = fmaf(f_, cst, i_ * g_);                                             \
        const float hv = o_ * (1.0f - 2.0f * __builtin_amdgcn_rcpf(__expf(2.0f * cst) + 1.0f)); \
        if (q < RPBK) {                                                           \
            HS[(P) ^ 1][q][u] = (_Float16)hv;                                     \
            if ((S) == SEQN - 1)                                                  \
                hFh[(size_t)(r0 + q) * HID + u] = (_Float16)hv;                   \
        }                                                                         \
        barrier_lds_only();                                                       \
    } while (0)

    for (int s2 = 0; s2 < SEQN; s2 += 2) {
        LSTM_STEP(s2,     0, eA, gxA, gxB);
        LSTM_STEP(s2 + 1, 1, eB, gxB, gxA);
    }
#undef LSTM_STEP
}

// ---------------------------------------------------------------------------
// FC + softmax, two-pass MFMA recompute (no max: |logit| < ~4).
// 196 blocks; persistent W_fc B-frags; loop over 16 row-groups.
//   pass A: block-local row-sums of exp(logits) -> Sp[row][bx] (row-major!)
//   reduce_s: S[row] = 1 / sum_bx Sp[row][bx]  (float4 + ILP)
//   pass B: exp(logit)*sinv staged in LDS, stored as contiguous float4 rows
// ---------------------------------------------------------------------------
__global__ void reduce_s(const float* __restrict__ Sp, float* __restrict__ S) {
    const int r = blockIdx.x * 256 + threadIdx.x;
    if (r < BATCH) {
        const float* p = Sp + (size_t)r * NBLKX;
        float a0 = 0.f, a1 = 0.f, a2 = 0.f, a3 = 0.f;
        for (int j = 0; j < NBLKX; j += 4) {            // 196 = 49*4
            const f32x4 v = *(const f32x4*)&p[j];
            a0 += v[0]; a1 += v[1]; a2 += v[2]; a3 += v[3];
        }
        S[r] = 1.0f / (a0 + a1 + a2 + a3);
    }
}

template <bool WRITE>
__global__ __launch_bounds__(256, 1)
void fc_pass(const _Float16* __restrict__ hFh, const float* __restrict__ W_fc,
             const float* __restrict__ b_fc, float* __restrict__ Sv,
             float* __restrict__ out)
{
    __shared__ float sinv[BATCH];                 // 4 KB (pass B)
    __shared__ float sred[4][64];                 // 1 KB (pass A)
    __shared__ __align__(16) float obuf[64][260]; // 66.5 KB (pass B staging)
    const int t    = threadIdx.x;
    const int w    = t >> 6;
    const int lane = t & 63;
    const int q    = lane >> 4;
    const int cc   = lane & 15;
    const int n0   = blockIdx.x * 256;

    if (WRITE) {
        for (int i = t; i < BATCH; i += 256) sinv[i] = Sv[i];
        __syncthreads();
    }

    // persistent B-frags: W_fc rows (cols of logits), clamped at NC
    half8 Bf[4][2];
    float bias[4];
#pragma unroll
    for (int nt = 0; nt < 4; ++nt) {
        int n = n0 + 64 * w + 16 * nt + cc;
        const int nl = (n < NC) ? n : NC - 1;
        bias[nt] = b_fc[nl];
#pragma unroll
        for (int kt = 0; kt < 2; ++kt) {
            const float* p = W_fc + (size_t)nl * HID + 32 * kt + 8 * q;
#pragma unroll
            for (int j = 0; j < 8; ++j) Bf[nt][kt][j] = (_Float16)p[j];
        }
    }

    for (int rg = 0; rg < BATCH / 64; ++rg) {
        const int row0 = rg * 64;

        // A-frags: h rows, fp16 direct
        half8 Af[4][2];
#pragma unroll
        for (int mt = 0; mt < 4; ++mt)
#pragma unroll
            for (int kt = 0; kt < 2; ++kt)
                Af[mt][kt] = *(const half8*)&hFh[(size_t)(row0 + 16 * mt + cc) * HID + 32 * kt + 8 * q];

        f32x4 acc[4][4];   // [mt][nt]
#pragma unroll
        for (int mt = 0; mt < 4; ++mt)
#pragma unroll
            for (int nt = 0; nt < 4; ++nt) acc[mt][nt] = (f32x4){0.f, 0.f, 0.f, 0.f};
#pragma unroll
        for (int mt = 0; mt < 4; ++mt)
#pragma unroll
            for (int nt = 0; nt < 4; ++nt)
#pragma unroll
                for (int kt = 0; kt < 2; ++kt)
                    acc[mt][nt] = __builtin_amdgcn_mfma_f32_16x16x32_f16(Af[mt][kt], Bf[nt][kt], acc[mt][nt], 0, 0, 0);

        if (!WRITE) {
            float rs[4][4];   // [mt][reg] partial row-sums over this wave's 64 cols
#pragma unroll
            for (int mt = 0; mt < 4; ++mt)
#pragma unroll
                for (int reg = 0; reg < 4; ++reg) rs[mt][reg] = 0.0f;
#pragma unroll
            for (int mt = 0; mt < 4; ++mt)
#pragma unroll
                for (int nt = 0; nt < 4; ++nt) {
                    const int n = n0 + 64 * w + 16 * nt + cc;
#pragma unroll
                    for (int reg = 0; reg < 4; ++reg) {
                        const float l = acc[mt][nt][reg] + bias[nt];
                        rs[mt][reg] += (n < NC) ? __expf(l) : 0.0f;
                    }
                }
#pragma unroll
            for (int mt = 0; mt < 4; ++mt)
#pragma unroll
                for (int reg = 0; reg < 4; ++reg) {
                    float v = rs[mt][reg];
                    v += __shfl_xor(v, 1);
                    v += __shfl_xor(v, 2);
                    v += __shfl_xor(v, 4);
                    v += __shfl_xor(v, 8);
                    rs[mt][reg] = v;
                }
            if (cc == 0) {
#pragma unroll
                for (int mt = 0; mt < 4; ++mt)
#pragma unroll
                    for (int reg = 0; reg < 4; ++reg)
                        sred[w][16 * mt + 4 * q + reg] = rs[mt][reg];
            }
            __syncthreads();
            if (t < 64)
                Sv[(size_t)(row0 + t) * NBLKX + blockIdx.x] =
                    sred[0][t] + sred[1][t] + sred[2][t] + sred[3][t];
            __syncthreads();   // sred reused next rg
        } else {
            // stage exp(l)*sinv into LDS tile, then store contiguous float4s
#pragma unroll
            for (int mt = 0; mt < 4; ++mt) {
                float si[4];
#pragma unroll
                for (int reg = 0; reg < 4; ++reg) si[reg] = sinv[row0 + 16 * mt + 4 * q + reg];
#pragma unroll
                for (int nt = 0; nt < 4; ++nt) {
#pragma unroll
                    for (int reg = 0; reg < 4; ++reg) {
                        const float l = acc[mt][nt][reg] + bias[nt];
                        obuf[16 * mt + 4 * q + reg][64 * w + 16 * nt + cc] = __expf(l) * si[reg];
                    }
                }
            }
            __syncthreads();
            const int lr = t >> 2;        // local row 0..63
            const int ch = t & 3;         // 64-col chunk
            const float* src = &obuf[lr][ch * 64];
            float* dst = out + (size_t)(row0 + lr) * NC + n0 + ch * 64;
            const int cbase0 = n0 + ch * 64;
            if (cbase0 + 64 <= NC) {
#pragma unroll
                for (int i = 0; i < 16; ++i)
                    *(f32x4*)&dst[4 * i] = *(const f32x4*)&src[4 * i];
            } else {
                for (int i = 0; i < 64; ++i)
                    if (cbase0 + i < NC) dst[i] = src[i];
            }
            __syncthreads();   // obuf reused next rg
        }
    }
}

extern "C" void kernel_launch(void* const* d_in, const int* in_sizes, int n_in,
                              void* d_out, int out_size, void* d_ws, size_t ws_size,
                              hipStream_t stream) {
    (void)in_sizes; (void)n_in; (void)out_size; (void)ws_size;
    const int*   x    = (const int*)  d_in[0];
    const float* emb  = (const float*)d_in[1];
    const float* W_ih = (const float*)d_in[2];
    const float* W_hh = (const float*)d_in[3];
    const float* b_ih = (const float*)d_in[4];
    const float* b_hh = (const float*)d_in[5];
    const float* W_fc = (const float*)d_in[6];
    const float* b_fc = (const float*)d_in[7];
    float* out = (float*)d_out;

    _Float16* hFh = (_Float16*)d_ws;                                  // 128 KB
    float* S  = (float*)((char*)d_ws + (size_t)BATCH * HID * 2);      // 4 KB
    float* Sp = S + BATCH;                                            // 1024*196 f32

    hipLaunchKernelGGL(lstm_rec, dim3(BATCH / RPBK), dim3(256), 0, stream,
                       x, emb, W_ih, W_hh, b_ih, b_hh, hFh);
    hipLaunchKernelGGL(fc_pass<false>, dim3(NBLKX), dim3(256), 0, stream,
                       hFh, W_fc, b_fc, Sp, out);
    hipLaunchKernelGGL(reduce_s, dim3(4), dim3(256), 0, stream, Sp, S);
    hipLaunchKernelGGL(fc_pass<true>,  dim3(NBLKX), dim3(256), 0, stream,
                       hFh, W_fc, b_fc, S, out);
}

// Round 4
// 573.566 us; speedup vs baseline: 1.6577x; 1.1033x over previous
//
#include <hip/hip_runtime.h>

#define BATCH 1024
#define SEQN  512
#define EMBD  50
#define HID   64
#define NC    50000
#define RPBK  2              // batch rows per LSTM block -> 512 blocks, 2/CU
#define HSTR  72             // h-tile row stride (fp16)
#define ESTR  72             // e-ring row stride (fp16)
#define CHUNK 16             // e-ring chunk depth (steps)
#define NBLKX ((NC + 255) / 256)   // 196 col-blocks in FC

typedef _Float16 half8 __attribute__((ext_vector_type(8)));
typedef float    f32x4 __attribute__((ext_vector_type(4)));

// barrier that does NOT drain vmcnt: LDS ordering via lgkmcnt(0) only.
__device__ __forceinline__ void barrier_lds_only() {
    asm volatile("s_waitcnt lgkmcnt(0)\n\ts_barrier" ::: "memory");
}

// ---------------------------------------------------------------------------
// Recurrent LSTM: 512 blocks x 256 thr, 2 rows/block (2 blocks/CU).
// Embedding gathers are CHUNKED: 16 steps' e fetched at once into regs
// (7 loads/thread), written to an LDS ring half at chunk boundaries.
// => zero global loads in 15/16 steps; the only vmcnt wait is for loads
// issued 16 steps (~6000 cy) earlier. Per step: 2 ds_read (HS) + 2 (ring) +
// 16 MFMA (e-MFMAs first; only h-MFMAs chain after barrier) + packed
// register epilogue on q==0 lanes (no cross-lane redistribution).
// ---------------------------------------------------------------------------
__global__ __launch_bounds__(256, 2)
void lstm_rec(const int* __restrict__ x, const float* __restrict__ emb,
              const float* __restrict__ W_ih, const float* __restrict__ W_hh,
              const float* __restrict__ b_ih, const float* __restrict__ b_hh,
              _Float16* __restrict__ hFh)
{
    __shared__ __align__(16) _Float16 HS[2][16][HSTR];          // rows 2..15 stay 0
    __shared__ __align__(16) _Float16 ER[2][CHUNK][RPBK][ESTR]; // e ring
    __shared__ int xbuf[RPBK * SEQN];

    const int t    = threadIdx.x;
    const int w    = t >> 6;
    const int lane = t & 63;
    const int q    = lane >> 4;
    const int cc   = lane & 15;
    const int r0   = blockIdx.x * RPBK;
    const int u    = 16 * w + cc;

    // persistent B-fragments: W_hh^T (kt 0,1) and W_ih^T (kt 0,1; k padded to 64)
    half8 Bh[2][4], Bi[2][4];
    float bias[4];
#pragma unroll
    for (int nt = 0; nt < 4; ++nt) {
        const int g = 64 * nt + u;
        bias[nt] = b_ih[g] + b_hh[g];
#pragma unroll
        for (int kt = 0; kt < 2; ++kt)
#pragma unroll
            for (int j = 0; j < 8; ++j) {
                const int k = 32 * kt + 8 * q + j;
                Bh[kt][nt][j] = (_Float16)W_hh[g * HID + k];
                Bi[kt][nt][j] = (k < EMBD) ? (_Float16)W_ih[g * EMBD + k] : (_Float16)0.0f;
            }
    }

    // stage token indices; zero HS (h0=0, pad rows) and ER (k-pad 50..63)
    for (int i = t; i < RPBK * SEQN; i += 256)
        xbuf[i] = x[(size_t)(r0 + (i >> 9)) * SEQN + (i & (SEQN - 1))];
    {
        _Float16* hz = &HS[0][0][0];
        for (int i = t; i < 2 * 16 * HSTR; i += 256) hz[i] = (_Float16)0.0f;
        _Float16* ez = &ER[0][0][0][0];
        for (int i = t; i < 2 * CHUNK * RPBK * ESTR; i += 256) ez[i] = (_Float16)0.0f;
    }
    __syncthreads();

    // chunk gather: 16 steps x 2 rows x 50 dims = 1600 vals, 7 loads/thread
    float ge[7];
#define GATHER(CH) do {                                                         \
        const int sb_ = (CH) * CHUNK;                                           \
        _Pragma("unroll")                                                       \
        for (int i = 0; i < 7; ++i) {                                           \
            const int idx = t + 256 * i;                                        \
            if (idx < CHUNK * RPBK * EMBD) {                                    \
                const int st_ = idx / (RPBK * EMBD);                            \
                const int rm_ = idx % (RPBK * EMBD);                            \
                const int rw_ = rm_ / EMBD;                                     \
                const int dm_ = rm_ % EMBD;                                     \
                int ss_ = sb_ + st_; if (ss_ > SEQN - 1) ss_ = SEQN - 1;        \
                ge[i] = emb[(size_t)xbuf[rw_ * SEQN + ss_] * EMBD + dm_];       \
            }                                                                   \
        }                                                                       \
    } while (0)
#define RINGW(CH) do {                                                          \
        const int hf_ = (CH) & 1;                                               \
        _Pragma("unroll")                                                       \
        for (int i = 0; i < 7; ++i) {                                           \
            const int idx = t + 256 * i;                                        \
            if (idx < CHUNK * RPBK * EMBD) {                                    \
                const int st_ = idx / (RPBK * EMBD);                            \
                const int rm_ = idx % (RPBK * EMBD);                            \
                const int rw_ = rm_ / EMBD;                                     \
                const int dm_ = rm_ % EMBD;                                     \
                ER[hf_][st_][rw_][dm_] = (_Float16)ge[i];                       \
            }                                                                   \
        }                                                                       \
    } while (0)

    GATHER(0);            // chunk 0 -> regs (compiler waits before RINGW)
    RINGW(0);             // ring half 0 <- chunk 0
    GATHER(1);            // chunk 1 in flight (consumed at s=15 boundary)
    barrier_lds_only();

    float cst0 = 0.0f, cst1 = 0.0f;

    for (int s = 0; s < SEQN; ++s) {
        const int pb = s & 1;
        const int hf = (s >> 4) & 1;
        const int st = s & 15;
        const int er = cc & 1;   // rows 2..15 of A read copies of rows 0/1

        // A-frags: h from HS (barrier-gated), e from ring (stable)
        const half8 Ae0 = *(const half8*)&ER[hf][st][er][8 * q];
        const half8 Ae1 = *(const half8*)&ER[hf][st][er][32 + 8 * q];
        const half8 Ah0 = *(const half8*)&HS[pb][cc][8 * q];
        const half8 Ah1 = *(const half8*)&HS[pb][cc][32 + 8 * q];

        // e-MFMAs first (no dependence on h); h-MFMAs chain last
        f32x4 acc[4];
#pragma unroll
        for (int nt = 0; nt < 4; ++nt) {
            f32x4 z = (f32x4){0.f, 0.f, 0.f, 0.f};
            z = __builtin_amdgcn_mfma_f32_16x16x32_f16(Ae0, Bi[0][nt], z, 0, 0, 0);
            z = __builtin_amdgcn_mfma_f32_16x16x32_f16(Ae1, Bi[1][nt], z, 0, 0, 0);
            z = __builtin_amdgcn_mfma_f32_16x16x32_f16(Ah0, Bh[0][nt], z, 0, 0, 0);
            acc[nt] = __builtin_amdgcn_mfma_f32_16x16x32_f16(Ah1, Bh[1][nt], z, 0, 0, 0);
        }

        // packed register epilogue on q==0 lanes: rows 0,1 in regs 0,1
        if (q == 0) {
            float p0[4], p1[4];
#pragma unroll
            for (int nt = 0; nt < 4; ++nt) {
                p0[nt] = acc[nt][0] + bias[nt];
                p1[nt] = acc[nt][1] + bias[nt];
            }
            const float i0 = __builtin_amdgcn_rcpf(1.0f + __expf(-p0[0]));
            const float f0 = __builtin_amdgcn_rcpf(1.0f + __expf(-p0[1]));
            const float g0 = 1.0f - 2.0f * __builtin_amdgcn_rcpf(__expf(2.0f * p0[2]) + 1.0f);
            const float o0 = __builtin_amdgcn_rcpf(1.0f + __expf(-p0[3]));
            const float i1 = __builtin_amdgcn_rcpf(1.0f + __expf(-p1[0]));
            const float f1 = __builtin_amdgcn_rcpf(1.0f + __expf(-p1[1]));
            const float g1 = 1.0f - 2.0f * __builtin_amdgcn_rcpf(__expf(2.0f * p1[2]) + 1.0f);
            const float o1 = __builtin_amdgcn_rcpf(1.0f + __expf(-p1[3]));
            cst0 = fmaf(f0, cst0, i0 * g0);
            cst1 = fmaf(f1, cst1, i1 * g1);
            const float h0 = o0 * (1.0f - 2.0f * __builtin_amdgcn_rcpf(__expf(2.0f * cst0) + 1.0f));
            const float h1 = o1 * (1.0f - 2.0f * __builtin_amdgcn_rcpf(__expf(2.0f * cst1) + 1.0f));
            HS[pb ^ 1][0][u] = (_Float16)h0;
            HS[pb ^ 1][1][u] = (_Float16)h1;
            if (s == SEQN - 1) {
                hFh[(size_t)r0 * HID + u]       = (_Float16)h0;
                hFh[(size_t)(r0 + 1) * HID + u] = (_Float16)h1;
            }
        }

        // chunk boundary: flush regs (chunk ch+1) to the idle ring half,
        // then issue gathers for chunk ch+2 (in flight for the next 16 steps)
        if (st == CHUNK - 1) {
            const int ch = s >> 4;
            RINGW(ch + 1);     // writes half (ch+1)&1; this chunk reads ch&1
            GATHER(ch + 2);
        }

        barrier_lds_only();
    }
#undef GATHER
#undef RINGW
}

// ---------------------------------------------------------------------------
// FC + softmax, single GEMM pass (no max: |logit| < ~4).
//   fc_exp : GEMM -> exp -> write UNNORMALIZED exp to out (205 MB) and
//            block-local row-sum partials -> Sp[row][bx]
//   reduce_s : S[row] = 1 / sum_bx Sp[row][bx]
//   scale_out: out *= S[row]  (pure float4 streaming, ~410 MB)
// Grid (196,2): by splits the 16 row-groups for occupancy.
// ---------------------------------------------------------------------------
__global__ __launch_bounds__(256, 2)
void fc_exp(const _Float16* __restrict__ hFh, const float* __restrict__ W_fc,
            const float* __restrict__ b_fc, float* __restrict__ Sp,
            float* __restrict__ out)
{
    __shared__ float sred[4][64];
    const int t    = threadIdx.x;
    const int w    = t >> 6;
    const int lane = t & 63;
    const int q    = lane >> 4;
    const int cc   = lane & 15;
    const int n0   = blockIdx.x * 256;

    // persistent B-frags: W_fc rows (cols of logits), clamped at NC
    half8 Bf[4][2];
    float bias[4];
#pragma unroll
    for (int nt = 0; nt < 4; ++nt) {
        int n = n0 + 64 * w + 16 * nt + cc;
        const int nl = (n < NC) ? n : NC - 1;
        bias[nt] = b_fc[nl];
#pragma unroll
        for (int kt = 0; kt < 2; ++kt) {
            const float* p = W_fc + (size_t)nl * HID + 32 * kt + 8 * q;
#pragma unroll
            for (int j = 0; j < 8; ++j) Bf[nt][kt][j] = (_Float16)p[j];
        }
    }

    const int rg0 = blockIdx.y * 8;
    for (int rg = rg0; rg < rg0 + 8; ++rg) {
        const int row0 = rg * 64;

        half8 Af[4][2];
#pragma unroll
        for (int mt = 0; mt < 4; ++mt)
#pragma unroll
            for (int kt = 0; kt < 2; ++kt)
                Af[mt][kt] = *(const half8*)&hFh[(size_t)(row0 + 16 * mt + cc) * HID + 32 * kt + 8 * q];

        f32x4 acc[4][4];   // [mt][nt]
#pragma unroll
        for (int mt = 0; mt < 4; ++mt)
#pragma unroll
            for (int nt = 0; nt < 4; ++nt) acc[mt][nt] = (f32x4){0.f, 0.f, 0.f, 0.f};
#pragma unroll
        for (int mt = 0; mt < 4; ++mt)
#pragma unroll
            for (int nt = 0; nt < 4; ++nt)
#pragma unroll
                for (int kt = 0; kt < 2; ++kt)
                    acc[mt][nt] = __builtin_amdgcn_mfma_f32_16x16x32_f16(Af[mt][kt], Bf[nt][kt], acc[mt][nt], 0, 0, 0);

        float rs[4][4];    // [mt][reg] partial row-sums over this wave's 64 cols
#pragma unroll
        for (int mt = 0; mt < 4; ++mt)
#pragma unroll
            for (int reg = 0; reg < 4; ++reg) rs[mt][reg] = 0.0f;

#pragma unroll
        for (int mt = 0; mt < 4; ++mt)
#pragma unroll
            for (int nt = 0; nt < 4; ++nt) {
                const int n = n0 + 64 * w + 16 * nt + cc;
                const bool ok = (n < NC);
#pragma unroll
                for (int reg = 0; reg < 4; ++reg) {
                    const float e = __expf(acc[mt][nt][reg] + bias[nt]);
                    rs[mt][reg] += ok ? e : 0.0f;
                    if (ok)
                        out[(size_t)(row0 + 16 * mt + 4 * q + reg) * NC + n] = e;
                }
            }

#pragma unroll
        for (int mt = 0; mt < 4; ++mt)
#pragma unroll
            for (int reg = 0; reg < 4; ++reg) {
                float v = rs[mt][reg];
                v += __shfl_xor(v, 1);
                v += __shfl_xor(v, 2);
                v += __shfl_xor(v, 4);
                v += __shfl_xor(v, 8);
                rs[mt][reg] = v;
            }
        if (cc == 0) {
#pragma unroll
            for (int mt = 0; mt < 4; ++mt)
#pragma unroll
                for (int reg = 0; reg < 4; ++reg)
                    sred[w][16 * mt + 4 * q + reg] = rs[mt][reg];
        }
        __syncthreads();
        if (t < 64)
            Sp[(size_t)(row0 + t) * NBLKX + blockIdx.x] =
                sred[0][t] + sred[1][t] + sred[2][t] + sred[3][t];
        __syncthreads();   // sred reused next rg
    }
}

__global__ void reduce_s(const float* __restrict__ Sp, float* __restrict__ S) {
    const int r = blockIdx.x * 256 + threadIdx.x;
    if (r < BATCH) {
        const float* p = Sp + (size_t)r * NBLKX;
        float a0 = 0.f, a1 = 0.f, a2 = 0.f, a3 = 0.f;
        for (int j = 0; j < NBLKX; j += 4) {            // 196 = 49*4
            const f32x4 v = *(const f32x4*)&p[j];
            a0 += v[0]; a1 += v[1]; a2 += v[2]; a3 += v[3];
        }
        S[r] = 1.0f / (a0 + a1 + a2 + a3);
    }
}

__global__ __launch_bounds__(256, 4)
void scale_out(float* __restrict__ out, const float* __restrict__ S) {
    const int row = blockIdx.y;
    const float si = S[row];
    f32x4* o = (f32x4*)(out + (size_t)row * NC);
    for (int i = blockIdx.x * 256 + threadIdx.x; i < NC / 4; i += 13 * 256) {
        f32x4 v = o[i];
        v[0] *= si; v[1] *= si; v[2] *= si; v[3] *= si;
        o[i] = v;
    }
}

extern "C" void kernel_launch(void* const* d_in, const int* in_sizes, int n_in,
                              void* d_out, int out_size, void* d_ws, size_t ws_size,
                              hipStream_t stream) {
    (void)in_sizes; (void)n_in; (void)out_size; (void)ws_size;
    const int*   x    = (const int*)  d_in[0];
    const float* emb  = (const float*)d_in[1];
    const float* W_ih = (const float*)d_in[2];
    const float* W_hh = (const float*)d_in[3];
    const float* b_ih = (const float*)d_in[4];
    const float* b_hh = (const float*)d_in[5];
    const float* W_fc = (const float*)d_in[6];
    const float* b_fc = (const float*)d_in[7];
    float* out = (float*)d_out;

    _Float16* hFh = (_Float16*)d_ws;                                  // 128 KB
    float* S  = (float*)((char*)d_ws + (size_t)BATCH * HID * 2);      // 4 KB
    float* Sp = S + BATCH;                                            // 1024*196 f32

    hipLaunchKernelGGL(lstm_rec, dim3(BATCH / RPBK), dim3(256), 0, stream,
                       x, emb, W_ih, W_hh, b_ih, b_hh, hFh);
    hipLaunchKernelGGL(fc_exp, dim3(NBLKX, 2), dim3(256), 0, stream,
                       hFh, W_fc, b_fc, Sp, out);
    hipLaunchKernelGGL(reduce_s, dim3(4), dim3(256), 0, stream, Sp, S);
    hipLaunchKernelGGL(scale_out, dim3(13, BATCH), dim3(256), 0, stream, out, S);
}

// Round 5
// 460.020 us; speedup vs baseline: 2.0669x; 1.2468x over previous
//
#include <hip/hip_runtime.h>

#define BATCH 1024
#define SEQN  512
#define EMBD  50
#define HID   64
#define NC    50000
#define RPBK  4              // batch rows per LSTM block -> 256 blocks, 1/CU
#define HSTR  72             // h-tile row stride (fp16)
#define ESTR  72             // e-ring row stride (fp16)
#define CHUNK 16             // e-ring chunk depth (steps)
#define GELT  (CHUNK * RPBK * EMBD)   // 3200 gather elems / chunk
#define NBLKX ((NC + 255) / 256)      // 196 col-blocks in FC

typedef _Float16 half8 __attribute__((ext_vector_type(8)));
typedef float    f32x4 __attribute__((ext_vector_type(4)));

// barrier that does NOT drain vmcnt: LDS ordering via lgkmcnt(0) only.
__device__ __forceinline__ void barrier_lds_only() {
    asm volatile("s_waitcnt lgkmcnt(0)\n\ts_barrier" ::: "memory");
}

// ---------------------------------------------------------------------------
// Recurrent LSTM: 256 blocks x 256 thr, 4 rows/block (1 block/CU).
// A rows replicated 4x (A[m] = X[m>>2]) => C rows 4q..4q+3 all hold batch
// row q's gates: lane (q,cc) takes acc[nt][0] directly -- one gate-set per
// lane, 10 trans instrs/wave/step (was 20), no shuffles, no selects.
// e-GEMM software-pipelined one step ahead (z ping-pong); embedding gathers
// chunked 16 steps deep into an LDS ring, flushed mid-chunk (st==8) so the
// boundary z-read is 7 barriers behind its producer. One lgkmcnt-only
// barrier per step; gathers stay vmcnt-outstanding across it.
// ---------------------------------------------------------------------------
__global__ __launch_bounds__(256, 1)
void lstm_rec(const int* __restrict__ x, const float* __restrict__ emb,
              const float* __restrict__ W_ih, const float* __restrict__ W_hh,
              const float* __restrict__ b_ih, const float* __restrict__ b_hh,
              _Float16* __restrict__ hFh)
{
    __shared__ __align__(16) _Float16 HS[2][RPBK][HSTR];
    __shared__ __align__(16) _Float16 ER[2][CHUNK][RPBK][ESTR];
    __shared__ int xbuf[RPBK * SEQN];

    const int t    = threadIdx.x;
    const int w    = t >> 6;
    const int lane = t & 63;
    const int q    = lane >> 4;
    const int cc   = lane & 15;
    const int r0   = blockIdx.x * RPBK;
    const int u    = 16 * w + cc;
    const int ar   = cc >> 2;      // A-row replication: A[m] = X[m>>2]

    // persistent B-fragments: W_hh^T (critical) and W_ih^T (k padded to 64)
    half8 Bh[2][4], Bi[2][4];
    float bias[4];
#pragma unroll
    for (int nt = 0; nt < 4; ++nt) {
        const int g = 64 * nt + u;
        bias[nt] = b_ih[g] + b_hh[g];
#pragma unroll
        for (int kt = 0; kt < 2; ++kt)
#pragma unroll
            for (int j = 0; j < 8; ++j) {
                const int k = 32 * kt + 8 * q + j;
                Bh[kt][nt][j] = (_Float16)W_hh[g * HID + k];
                Bi[kt][nt][j] = (k < EMBD) ? (_Float16)W_ih[g * EMBD + k] : (_Float16)0.0f;
            }
    }

    // stage token indices; zero HS (h0=0) and ER (k-pad 50..63)
    for (int i = t; i < RPBK * SEQN; i += 256)
        xbuf[i] = x[(size_t)(r0 + (i >> 9)) * SEQN + (i & (SEQN - 1))];
    {
        _Float16* hz = &HS[0][0][0];
        for (int i = t; i < 2 * RPBK * HSTR; i += 256) hz[i] = (_Float16)0.0f;
        _Float16* ez = &ER[0][0][0][0];
        for (int i = t; i < 2 * CHUNK * RPBK * ESTR; i += 256) ez[i] = (_Float16)0.0f;
    }
    __syncthreads();

    // chunk gather: 16 steps x 4 rows x 50 dims = 3200 vals, 13 loads/thread
    float ge[13];
#define GATHER(CH) do {                                                         \
        const int sb_ = (CH) * CHUNK;                                           \
        _Pragma("unroll")                                                       \
        for (int i = 0; i < 13; ++i) {                                          \
            const int idx = t + 256 * i;                                        \
            if (idx < GELT) {                                                   \
                const int st_ = idx / (RPBK * EMBD);                            \
                const int rm_ = idx % (RPBK * EMBD);                            \
                const int rw_ = rm_ / EMBD;                                     \
                const int dm_ = rm_ % EMBD;                                     \
                int ss_ = sb_ + st_; if (ss_ > SEQN - 1) ss_ = SEQN - 1;        \
                ge[i] = emb[(size_t)xbuf[rw_ * SEQN + ss_] * EMBD + dm_];       \
            }                                                                   \
        }                                                                       \
    } while (0)
#define RINGW(CH) do {                                                          \
        const int hf_ = (CH) & 1;                                               \
        _Pragma("unroll")                                                       \
        for (int i = 0; i < 13; ++i) {                                          \
            const int idx = t + 256 * i;                                        \
            if (idx < GELT) {                                                   \
                const int st_ = idx / (RPBK * EMBD);                            \
                const int rm_ = idx % (RPBK * EMBD);                            \
                const int rw_ = rm_ / EMBD;                                     \
                const int dm_ = rm_ % EMBD;                                     \
                ER[hf_][st_][rw_][dm_] = (_Float16)ge[i];                       \
            }                                                                   \
        }                                                                       \
    } while (0)

    GATHER(0);            // chunk 0 -> regs (dep stall once)
    RINGW(0);             // ring half 0 <- chunk 0
    GATHER(1);            // chunk 1 in flight (flushed at s=8)
    __syncthreads();

    // z(0) = e(0) @ W_ih^T
    f32x4 zA[4], zB[4];
    {
        const half8 Ae0 = *(const half8*)&ER[0][0][ar][8 * q];
        const half8 Ae1 = *(const half8*)&ER[0][0][ar][32 + 8 * q];
#pragma unroll
        for (int nt = 0; nt < 4; ++nt) {
            f32x4 zz = (f32x4){0.f, 0.f, 0.f, 0.f};
            zz = __builtin_amdgcn_mfma_f32_16x16x32_f16(Ae0, Bi[0][nt], zz, 0, 0, 0);
            zA[nt] = __builtin_amdgcn_mfma_f32_16x16x32_f16(Ae1, Bi[1][nt], zz, 0, 0, 0);
        }
    }

    float cst = 0.0f;   // c for (row q, unit u)

#define LSTM_STEP(S, PB, ZIN, ZOUT) do {                                          \
        /* critical: A-frags of h(s), rows replicated (ar = cc>>2) */             \
        const half8 Ah0 = *(const half8*)&HS[PB][ar][8 * q];                      \
        const half8 Ah1 = *(const half8*)&HS[PB][ar][32 + 8 * q];                 \
        f32x4 acc[4];                                                             \
        _Pragma("unroll")                                                         \
        for (int nt = 0; nt < 4; ++nt) {                                          \
            f32x4 t1 = __builtin_amdgcn_mfma_f32_16x16x32_f16(Ah0, Bh[0][nt], ZIN[nt], 0, 0, 0); \
            acc[nt] = __builtin_amdgcn_mfma_f32_16x16x32_f16(Ah1, Bh[1][nt], t1, 0, 0, 0); \
        }                                                                         \
        /* off-path: z(s+1) = e(s+1) @ W_ih^T from stable ring */                 \
        {                                                                         \
            const int sn  = ((S) + 1 < SEQN) ? (S) + 1 : SEQN - 1;                \
            const int hfn = (sn >> 4) & 1;                                        \
            const int stn = sn & 15;                                              \
            const half8 Ae0 = *(const half8*)&ER[hfn][stn][ar][8 * q];            \
            const half8 Ae1 = *(const half8*)&ER[hfn][stn][ar][32 + 8 * q];       \
            _Pragma("unroll")                                                     \
            for (int nt = 0; nt < 4; ++nt) {                                      \
                f32x4 t2 = (f32x4){0.f, 0.f, 0.f, 0.f};                           \
                t2 = __builtin_amdgcn_mfma_f32_16x16x32_f16(Ae0, Bi[0][nt], t2, 0, 0, 0); \
                ZOUT[nt] = __builtin_amdgcn_mfma_f32_16x16x32_f16(Ae1, Bi[1][nt], t2, 0, 0, 0); \
            }                                                                     \
        }                                                                         \
        /* one gate-set per lane: row q, unit u, value in acc[nt][0] */           \
        const float p0 = acc[0][0] + bias[0];                                     \
        const float p1 = acc[1][0] + bias[1];                                     \
        const float p2 = acc[2][0] + bias[2];                                     \
        const float p3 = acc[3][0] + bias[3];                                     \
        const float i_ = __builtin_amdgcn_rcpf(1.0f + __expf(-p0));               \
        const float f_ = __builtin_amdgcn_rcpf(1.0f + __expf(-p1));               \
        const float g_ = 1.0f - 2.0f * __builtin_amdgcn_rcpf(__expf(2.0f * p2) + 1.0f); \
        const float o_ = __builtin_amdgcn_rcpf(1.0f + __expf(-p3));               \
        cst = fmaf(f_, cst, i_ * g_);                                             \
        const float hv = o_ * (1.0f - 2.0f * __builtin_amdgcn_rcpf(__expf(2.0f * cst) + 1.0f)); \
        HS[(PB) ^ 1][q][u] = (_Float16)hv;                                        \
        if ((S) == SEQN - 1)                                                      \
            hFh[(size_t)(r0 + q) * HID + u] = (_Float16)hv;                       \
        /* mid-chunk: flush regs (chunk ch+1) to idle half, gather ch+2 */        \
        if (((S) & 15) == 8) {                                                    \
            const int ch = (S) >> 4;                                              \
            RINGW(ch + 1);                                                        \
            GATHER(ch + 2);                                                       \
        }                                                                         \
        barrier_lds_only();                                                       \
    } while (0)

    for (int s2 = 0; s2 < SEQN; s2 += 2) {
        LSTM_STEP(s2,     0, zA, zB);
        LSTM_STEP(s2 + 1, 1, zB, zA);
    }
#undef LSTM_STEP
#undef GATHER
#undef RINGW
}

// ---------------------------------------------------------------------------
// FC + softmax (no max: |logit| < ~4).
//   fc_sum  : GEMM+exp+rowsum only (no global stores) -> Sp[row][bx]
//   reduce_s: S[row] = 1 / sum_bx Sp[row][bx]
//   fc_write: recompute GEMM, exp*sinv -> LDS tile -> wave-coalesced 1KB
//             float4 row stores. out written exactly once (205 MB).
// ---------------------------------------------------------------------------
__global__ __launch_bounds__(256, 2)
void fc_sum(const _Float16* __restrict__ hFh, const float* __restrict__ W_fc,
            const float* __restrict__ b_fc, float* __restrict__ Sp)
{
    __shared__ float sred[4][64];
    const int t    = threadIdx.x;
    const int w    = t >> 6;
    const int lane = t & 63;
    const int q    = lane >> 4;
    const int cc   = lane & 15;
    const int n0   = blockIdx.x * 256;

    half8 Bf[4][2];
    float bias[4];
#pragma unroll
    for (int nt = 0; nt < 4; ++nt) {
        int n = n0 + 64 * w + 16 * nt + cc;
        const int nl = (n < NC) ? n : NC - 1;
        bias[nt] = b_fc[nl];
#pragma unroll
        for (int kt = 0; kt < 2; ++kt) {
            const float* p = W_fc + (size_t)nl * HID + 32 * kt + 8 * q;
#pragma unroll
            for (int j = 0; j < 8; ++j) Bf[nt][kt][j] = (_Float16)p[j];
        }
    }

    const int rg0 = blockIdx.y * 4;
    for (int rg = rg0; rg < rg0 + 4; ++rg) {
        const int row0 = rg * 64;

        half8 Af[4][2];
#pragma unroll
        for (int mt = 0; mt < 4; ++mt)
#pragma unroll
            for (int kt = 0; kt < 2; ++kt)
                Af[mt][kt] = *(const half8*)&hFh[(size_t)(row0 + 16 * mt + cc) * HID + 32 * kt + 8 * q];

        f32x4 acc[4][4];
#pragma unroll
        for (int mt = 0; mt < 4; ++mt)
#pragma unroll
            for (int nt = 0; nt < 4; ++nt) acc[mt][nt] = (f32x4){0.f, 0.f, 0.f, 0.f};
#pragma unroll
        for (int mt = 0; mt < 4; ++mt)
#pragma unroll
            for (int nt = 0; nt < 4; ++nt)
#pragma unroll
                for (int kt = 0; kt < 2; ++kt)
                    acc[mt][nt] = __builtin_amdgcn_mfma_f32_16x16x32_f16(Af[mt][kt], Bf[nt][kt], acc[mt][nt], 0, 0, 0);

        float rs[4][4];
#pragma unroll
        for (int mt = 0; mt < 4; ++mt)
#pragma unroll
            for (int reg = 0; reg < 4; ++reg) rs[mt][reg] = 0.0f;
#pragma unroll
        for (int mt = 0; mt < 4; ++mt)
#pragma unroll
            for (int nt = 0; nt < 4; ++nt) {
                const int n = n0 + 64 * w + 16 * nt + cc;
                const bool ok = (n < NC);
#pragma unroll
                for (int reg = 0; reg < 4; ++reg) {
                    const float e = __expf(acc[mt][nt][reg] + bias[nt]);
                    rs[mt][reg] += ok ? e : 0.0f;
                }
            }
#pragma unroll
        for (int mt = 0; mt < 4; ++mt)
#pragma unroll
            for (int reg = 0; reg < 4; ++reg) {
                float v = rs[mt][reg];
                v += __shfl_xor(v, 1);
                v += __shfl_xor(v, 2);
                v += __shfl_xor(v, 4);
                v += __shfl_xor(v, 8);
                rs[mt][reg] = v;
            }
        if (cc == 0) {
#pragma unroll
            for (int mt = 0; mt < 4; ++mt)
#pragma unroll
                for (int reg = 0; reg < 4; ++reg)
                    sred[w][16 * mt + 4 * q + reg] = rs[mt][reg];
        }
        __syncthreads();
        if (t < 64)
            Sp[(size_t)(row0 + t) * NBLKX + blockIdx.x] =
                sred[0][t] + sred[1][t] + sred[2][t] + sred[3][t];
        __syncthreads();
    }
}

__global__ void reduce_s(const float* __restrict__ Sp, float* __restrict__ S) {
    const int r = blockIdx.x * 256 + threadIdx.x;
    if (r < BATCH) {
        const float* p = Sp + (size_t)r * NBLKX;
        float a0 = 0.f, a1 = 0.f, a2 = 0.f, a3 = 0.f;
        for (int j = 0; j < NBLKX; j += 4) {            // 196 = 49*4
            const f32x4 v = *(const f32x4*)&p[j];
            a0 += v[0]; a1 += v[1]; a2 += v[2]; a3 += v[3];
        }
        S[r] = 1.0f / (a0 + a1 + a2 + a3);
    }
}

__global__ __launch_bounds__(256, 2)
void fc_write(const _Float16* __restrict__ hFh, const float* __restrict__ W_fc,
              const float* __restrict__ b_fc, const float* __restrict__ S,
              float* __restrict__ out)
{
    __shared__ float sinv2[256];
    __shared__ __align__(16) float obuf[64][260];
    const int t    = threadIdx.x;
    const int w    = t >> 6;
    const int lane = t & 63;
    const int q    = lane >> 4;
    const int cc   = lane & 15;
    const int n0   = blockIdx.x * 256;

    sinv2[t] = S[blockIdx.y * 256 + t];

    half8 Bf[4][2];
    float bias[4];
#pragma unroll
    for (int nt = 0; nt < 4; ++nt) {
        int n = n0 + 64 * w + 16 * nt + cc;
        const int nl = (n < NC) ? n : NC - 1;
        bias[nt] = b_fc[nl];
#pragma unroll
        for (int kt = 0; kt < 2; ++kt) {
            const float* p = W_fc + (size_t)nl * HID + 32 * kt + 8 * q;
#pragma unroll
            for (int j = 0; j < 8; ++j) Bf[nt][kt][j] = (_Float16)p[j];
        }
    }
    __syncthreads();

    const int rg0 = blockIdx.y * 4;
#pragma unroll 1
    for (int rr = 0; rr < 4; ++rr) {
        const int row0 = (rg0 + rr) * 64;

        half8 Af[4][2];
#pragma unroll
        for (int mt = 0; mt < 4; ++mt)
#pragma unroll
            for (int kt = 0; kt < 2; ++kt)
                Af[mt][kt] = *(const half8*)&hFh[(size_t)(row0 + 16 * mt + cc) * HID + 32 * kt + 8 * q];

        f32x4 acc[4][4];
#pragma unroll
        for (int mt = 0; mt < 4; ++mt)
#pragma unroll
            for (int nt = 0; nt < 4; ++nt) acc[mt][nt] = (f32x4){0.f, 0.f, 0.f, 0.f};
#pragma unroll
        for (int mt = 0; mt < 4; ++mt)
#pragma unroll
            for (int nt = 0; nt < 4; ++nt)
#pragma unroll
                for (int kt = 0; kt < 2; ++kt)
                    acc[mt][nt] = __builtin_amdgcn_mfma_f32_16x16x32_f16(Af[mt][kt], Bf[nt][kt], acc[mt][nt], 0, 0, 0);

        // exp * sinv -> LDS tile (identical exp sequence to fc_sum)
#pragma unroll
        for (int mt = 0; mt < 4; ++mt)
#pragma unroll
            for (int nt = 0; nt < 4; ++nt)
#pragma unroll
                for (int reg = 0; reg < 4; ++reg) {
                    const int lr = 16 * mt + 4 * q + reg;
                    const float e = __expf(acc[mt][nt][reg] + bias[nt]);
                    obuf[lr][64 * w + 16 * nt + cc] = e * sinv2[rr * 64 + lr];
                }
        __syncthreads();

        // wave-coalesced stores: per instr, 64 lanes x float4 = 1KB contiguous
        const int col = 4 * lane;
        if (n0 + col < NC) {
#pragma unroll
            for (int i = 0; i < 16; ++i) {
                const int row = 16 * w + i;
                *(f32x4*)&out[(size_t)(row0 + row) * NC + n0 + col] =
                    *(const f32x4*)&obuf[row][col];
            }
        }
        __syncthreads();
    }
}

extern "C" void kernel_launch(void* const* d_in, const int* in_sizes, int n_in,
                              void* d_out, int out_size, void* d_ws, size_t ws_size,
                              hipStream_t stream) {
    (void)in_sizes; (void)n_in; (void)out_size; (void)ws_size;
    const int*   x    = (const int*)  d_in[0];
    const float* emb  = (const float*)d_in[1];
    const float* W_ih = (const float*)d_in[2];
    const float* W_hh = (const float*)d_in[3];
    const float* b_ih = (const float*)d_in[4];
    const float* b_hh = (const float*)d_in[5];
    const float* W_fc = (const float*)d_in[6];
    const float* b_fc = (const float*)d_in[7];
    float* out = (float*)d_out;

    _Float16* hFh = (_Float16*)d_ws;                                  // 128 KB
    float* S  = (float*)((char*)d_ws + (size_t)BATCH * HID * 2);      // 4 KB
    float* Sp = S + BATCH;                                            // 1024*196 f32

    hipLaunchKernelGGL(lstm_rec, dim3(BATCH / RPBK), dim3(256), 0, stream,
                       x, emb, W_ih, W_hh, b_ih, b_hh, hFh);
    hipLaunchKernelGGL(fc_sum,   dim3(NBLKX, 4), dim3(256), 0, stream,
                       hFh, W_fc, b_fc, Sp);
    hipLaunchKernelGGL(reduce_s, dim3(4), dim3(256), 0, stream, Sp, S);
    hipLaunchKernelGGL(fc_write, dim3(NBLKX, 4), dim3(256), 0, stream,
                       hFh, W_fc, b_fc, S, out);
}